// Round 18
// baseline (152.297 us; speedup 1.0000x reference)
//
#include <hip/hip_runtime.h>

typedef unsigned short u16;
typedef unsigned int u32;
typedef __bf16 bf16x8_t __attribute__((ext_vector_type(8)));
typedef float f32x4 __attribute__((ext_vector_type(4)));
typedef float f32x16 __attribute__((ext_vector_type(16)));

__device__ __forceinline__ u16 f2b(float f) {
  union { float f; u32 u; } v; v.f = f;
  u32 r = v.u + 0x7fffu + ((v.u >> 16) & 1u);
  return (u16)(r >> 16);
}

__device__ __forceinline__ u32 pkbf(float a, float b) {
  union { __bf16 h[2]; u32 u; } v;
  v.h[0] = (__bf16)a; v.h[1] = (__bf16)b;
  return v.u;
}

// fragment-major offset for bf16 matrices [M rows][Kd cols]: 16x8 tiles;
// an MFMA A/B-operand wave-load is 1KB contiguous.
__device__ __forceinline__ size_t fmoff(int r, int c, int Kd) {
  return ((size_t)(r >> 4) * (Kd >> 3) + (c >> 3)) * 128 + (r & 15) * 8 + (c & 7);
}

__device__ __forceinline__ f32x4 mfma16(uint4 a, uint4 b, f32x4 c) {
  return __builtin_amdgcn_mfma_f32_16x16x32_bf16(
      __builtin_bit_cast(bf16x8_t, a), __builtin_bit_cast(bf16x8_t, b), c, 0, 0, 0);
}

__device__ __forceinline__ f32x16 mfma32(uint4 a, uint4 b, f32x16 c) {
  return __builtin_amdgcn_mfma_f32_32x32x16_bf16(
      __builtin_bit_cast(bf16x8_t, a), __builtin_bit_cast(bf16x8_t, b), c, 0, 0, 0);
}

__device__ __forceinline__ void plswap(u32& a, u32& b) {
  asm("v_permlane32_swap_b32 %0, %1" : "+v"(a), "+v"(b));
}

__device__ __forceinline__ void load_lds16(const void* g, void* l) {
  __builtin_amdgcn_global_load_lds(
      (const __attribute__((address_space(1))) unsigned int*)g,
      (__attribute__((address_space(3))) unsigned int*)l, 16, 0, 0);
}

template <int N>
__device__ __forceinline__ void waitvm() {
  if constexpr (N == 0) asm volatile("s_waitcnt vmcnt(0)" ::: "memory");
  else if constexpr (N == 4) asm volatile("s_waitcnt vmcnt(4)" ::: "memory");
  else if constexpr (N == 6) asm volatile("s_waitcnt vmcnt(6)" ::: "memory");
  else if constexpr (N == 8) asm volatile("s_waitcnt vmcnt(8)" ::: "memory");
  else if constexpr (N == 10) asm volatile("s_waitcnt vmcnt(10)" ::: "memory");
  else asm volatile("s_waitcnt vmcnt(12)" ::: "memory");
}

// ---------------- LayerNorm row body: 384 f32 -> bf16 fragment-major --------
__device__ __forceinline__ void ln_body(const float* __restrict__ x,
                                        const float* __restrict__ g,
                                        const float* __restrict__ bta,
                                        u16* __restrict__ out, int row,
                                        int lane) {
  const float* xr = x + (size_t)row * 384;
  float v[6];
  float s = 0.f;
#pragma unroll
  for (int i = 0; i < 6; i++) { v[i] = xr[i * 64 + lane]; s += v[i]; }
#pragma unroll
  for (int off = 32; off >= 1; off >>= 1) s += __shfl_xor(s, off);
  float mean = s * (1.0f / 384.0f);
  float vs = 0.f;
#pragma unroll
  for (int i = 0; i < 6; i++) { float d = v[i] - mean; vs += d * d; }
#pragma unroll
  for (int off = 32; off >= 1; off >>= 1) vs += __shfl_xor(vs, off);
  float rstd = rsqrtf(vs * (1.0f / 384.0f) + 1e-5f);
#pragma unroll
  for (int i = 0; i < 6; i++) {
    int c = i * 64 + lane;
    out[fmoff(row, c, 384)] = f2b((v[i] - mean) * rstd * g[c] + bta[c]);
  }
}

// ---------------- prep: weight transposes (tiles 0..431) + ln1 (rest) -------
// qkv/fc1/fc2 -> row-major [N,K] (LDS-GEMM); proj -> fragment-major.
__global__ __launch_bounds__(256) void prep_k(
    const float* __restrict__ w0, u16* __restrict__ t0_,
    const float* __restrict__ w1, u16* __restrict__ t1_,
    const float* __restrict__ w2, u16* __restrict__ t2_,
    const float* __restrict__ w3, u16* __restrict__ t3_,
    const float* __restrict__ x, const float* __restrict__ g,
    const float* __restrict__ bta, u16* __restrict__ lnout) {
  __shared__ u16 L[64][68];
  int tile = blockIdx.x, tid = threadIdx.x;
  if (tile >= 432) {
    ln_body(x, g, bta, lnout, (tile - 432) * 4 + (tid >> 6), tid & 63);
    return;
  }
  const float* w; u16* wt; int K, N, rel; bool fm;
  if (tile < 108)      { w = w0; wt = t0_; K = 384;  N = 1152; rel = tile;       fm = false; }
  else if (tile < 144) { w = w1; wt = t1_; K = 384;  N = 384;  rel = tile - 108; fm = true; }
  else if (tile < 288) { w = w2; wt = t2_; K = 384;  N = 1536; rel = tile - 144; fm = false; }
  else                 { w = w3; wt = t3_; K = 1536; N = 384;  rel = tile - 288; fm = false; }
  int ntx = N >> 6;
  int tk = (rel / ntx) << 6, tn = (rel - (rel / ntx) * ntx) << 6;

  int r = tid >> 2, c0 = (tid & 3) << 4;
  const float* src = w + (size_t)(tk + r) * N + tn + c0;
#pragma unroll
  for (int j = 0; j < 16; j += 4) {
    float4 a = *(const float4*)(src + j);
    L[r][c0 + j + 0] = f2b(a.x);
    L[r][c0 + j + 1] = f2b(a.y);
    L[r][c0 + j + 2] = f2b(a.z);
    L[r][c0 + j + 3] = f2b(a.w);
  }
  __syncthreads();
  int n = tid >> 2, k0 = (tid & 3) << 4;
  u16 tmp[16];
#pragma unroll
  for (int j = 0; j < 16; j++) tmp[j] = L[k0 + j][n];
  if (fm) {
    u16* dst = wt + fmoff(tn + n, tk + k0, K);
    *(uint4*)dst = *(const uint4*)(tmp);
    *(uint4*)(dst + 128) = *(const uint4*)(tmp + 8);
  } else {
    u16* dst = wt + (size_t)(tn + n) * K + tk + k0;
    *(uint4*)dst = *(const uint4*)(tmp);
    *(uint4*)(dst + 8) = *(const uint4*)(tmp + 8);
  }
}

// ---------------- GEMM (R13): A fm direct-to-reg, B LDS triple-buffer -------
template <int EPI, int MR, int KD, int NX, int MINW>
__global__ __launch_bounds__(256, MINW) void gemm_k(
    const u16* __restrict__ A, const u16* __restrict__ Bt,
    const float* __restrict__ bias, const float* __restrict__ res,
    void* __restrict__ outp, int Nn,
    u16* __restrict__ qp, u16* __restrict__ kp, u16* __restrict__ vtp) {
  constexpr int NS = KD / 64;
  constexpr int KD8 = KD / 8;
  __shared__ __align__(16) u16 Bs[3][64 * 64];
  int tid = threadIdx.x;
  int lane = tid & 63, wid = tid >> 6;
  int li = lane & 15, lg = lane >> 4;
  int wr = wid >> 1, wc = wid & 1;

  int p = blockIdx.x;
  int idx = p >> 3;
  int cx = idx % NX;
  int row0 = ((p & 7) + ((idx / NX) << 3)) * (MR * 32);
  int col0 = cx * 64;

  int lr = lane >> 3;
  int sc8 = ((lane & 7) ^ lr) * 8;

  const u16* Ab = A + ((size_t)(row0 / 16 + wr * MR) * KD8 + lg) * 128 + li * 8;

  f32x4 z = {0.f, 0.f, 0.f, 0.f};
  f32x4 acc[MR][2];
#pragma unroll
  for (int m = 0; m < MR; m++)
#pragma unroll
    for (int n = 0; n < 2; n++) acc[m][n] = z;

  uint4 af0[MR][2], af1[MR][2];

  auto stageB = [&](int buf, int k0) {
#pragma unroll
    for (int j = 0; j < 2; j++) {
      int ib = wid * 2 + j;
      load_lds16(Bt + (size_t)(col0 + ib * 8 + lr) * KD + k0 + sc8,
                 (char*)Bs[buf] + ib * 1024);
    }
  };
  auto loadA = [&](uint4 (*dst)[2], int t) {
#pragma unroll
    for (int m = 0; m < MR; m++)
#pragma unroll
      for (int kk = 0; kk < 2; kk++)
        dst[m][kk] =
            *(const uint4*)(Ab + ((size_t)m * KD8 + t * 8 + kk * 4) * 128);
  };

  stageB(0, 0);
  stageB(1, 64);
  loadA(af0, 0);
  if (NS > 1) loadA(af1, 1);
  waitvm<2 * MR>();
  __builtin_amdgcn_s_barrier();
  asm volatile("" ::: "memory");

#pragma unroll
  for (int t = 0; t < NS; t++) {
    if (t + 2 < NS) stageB((t + 2) % 3, (t + 2) * 64);
    const char* Bsb = (const char*)Bs[t % 3];
#pragma unroll
    for (int kk = 0; kk < 2; kk++) {
      uint4 bf[2];
#pragma unroll
      for (int n = 0; n < 2; n++) {
        int c = wc * 32 + n * 16 + li;
        bf[n] = *(const uint4*)(Bsb + c * 128 +
                                ((kk * 64 + lg * 16) ^ ((c & 7) << 4)));
      }
#pragma unroll
      for (int m = 0; m < MR; m++)
#pragma unroll
        for (int n = 0; n < 2; n++)
          acc[m][n] = mfma16((t & 1) ? af1[m][kk] : af0[m][kk], bf[n],
                             acc[m][n]);
    }
    if (t + 2 < NS) {
      if (t & 1) loadA(af1, t + 2);
      else       loadA(af0, t + 2);
      waitvm<2 + 2 * MR>();
      __builtin_amdgcn_s_barrier();
      asm volatile("" ::: "memory");
    } else if (t + 1 < NS) {
      waitvm<0>();
      __builtin_amdgcn_s_barrier();
      asm volatile("" ::: "memory");
    }
  }

#pragma unroll
  for (int m = 0; m < MR; m++) {
#pragma unroll
    for (int n = 0; n < 2; n++) {
#pragma unroll
      for (int j = 0; j < 4; j++) {
        int r = row0 + wr * (MR * 16) + m * 16 + lg * 4 + j;
        int c = col0 + wc * 32 + n * 16 + li;
        float v = acc[m][n][j] + bias[c];
        if (EPI == 0) {
          ((float*)outp)[(size_t)r * Nn + c] = v + res[(size_t)r * Nn + c];
        } else if (EPI == 1) {
          float e = __expf(-1.5957691f * v * (1.f + 0.044715f * v * v));
          ((u16*)outp)[fmoff(r, c, Nn)] = f2b(v / (1.f + e));
        } else {
          int tt = c / 384;
          int c2 = c - tt * 384;
          int hh = c2 >> 6, d = c2 & 63;
          int bb = r >> 11, nn = r & 2047;
          size_t bh = (size_t)bb * 6 + hh;
          int tile = nn >> 5;
          if (tt == 2) {
            int kvl = nn & 31;
            int kvHalf = (kvl >> 4) & 1, h2 = (kvl >> 3) & 1, jj = kvl & 7;
            int dTile = d >> 5, l31 = d & 31;
            vtp[(((bh * 64 + tile) * 2 + dTile) * 2 + kvHalf) * 512 +
                (l31 + h2 * 32) * 8 + jj] = f2b(v);
          } else {
            int chunk = d >> 4, h2 = (d >> 3) & 1, e = d & 7;
            int l31 = nn & 31;
            size_t off = ((bh * 64 + tile) * 4 + chunk) * 512 +
                         (l31 + h2 * 32) * 8 + e;
            if (tt == 0) qp[off] = f2b(v * 0.18033688f);  // 0.125 * log2(e)
            else         kp[off] = f2b(v);
          }
        }
      }
    }
  }
}

// ---------------- fused proj + residual + LayerNorm2 (R16, proven) ----------
__global__ __launch_bounds__(256, 2) void projln_k(
    const u16* __restrict__ A, const u16* __restrict__ Bt,
    const float* __restrict__ bias, const float* __restrict__ x,
    const float* __restrict__ g2, const float* __restrict__ b2,
    float* __restrict__ x1, u16* __restrict__ h2) {
  __shared__ float Sm[4][16], Sv[4][16];
  int tid = threadIdx.x;
  int lane = tid & 63, wid = tid >> 6;
  int li = lane & 15, lg = lane >> 4;
  int r0 = blockIdx.x * 16;

  const u16* Ab = A + ((size_t)(r0 >> 4) * 48 + lg) * 128 + li * 8;
  const u16* Bb = Bt + ((size_t)(wid * 6) * 48 + lg) * 128 + li * 8;

  f32x4 z = {0.f, 0.f, 0.f, 0.f};
  f32x4 acc[6];
#pragma unroll
  for (int n = 0; n < 6; n++) acc[n] = z;

  uint4 af0[2], af1[2], bf0[6][2], bf1[6][2];
  auto loadA = [&](uint4* dst, int t) {
#pragma unroll
    for (int kk = 0; kk < 2; kk++)
      dst[kk] = *(const uint4*)(Ab + ((size_t)t * 8 + kk * 4) * 128);
  };
  auto loadB = [&](uint4 (*dst)[2], int t) {
#pragma unroll
    for (int n = 0; n < 6; n++)
#pragma unroll
      for (int kk = 0; kk < 2; kk++)
        dst[n][kk] =
            *(const uint4*)(Bb + ((size_t)n * 48 + t * 8 + kk * 4) * 128);
  };

  loadA(af0, 0);
  loadB(bf0, 0);
#pragma unroll
  for (int t = 0; t < 6; t++) {
    if (t + 1 < 6) {
      if (t & 1) { loadA(af0, t + 1); loadB(bf0, t + 1); }
      else       { loadA(af1, t + 1); loadB(bf1, t + 1); }
    }
#pragma unroll
    for (int kk = 0; kk < 2; kk++)
#pragma unroll
      for (int n = 0; n < 6; n++)
        acc[n] = mfma16((t & 1) ? af1[kk] : af0[kk],
                        (t & 1) ? bf1[n][kk] : bf0[n][kk], acc[n]);
  }

  float vv[6][4];
  float s1[4] = {0.f, 0.f, 0.f, 0.f}, s2[4] = {0.f, 0.f, 0.f, 0.f};
#pragma unroll
  for (int n = 0; n < 6; n++) {
    int c = wid * 96 + n * 16 + li;
    float bc = bias[c];
#pragma unroll
    for (int j = 0; j < 4; j++) {
      int r = r0 + lg * 4 + j;
      float v = acc[n][j] + bc + x[(size_t)r * 384 + c];
      vv[n][j] = v;
      x1[(size_t)r * 384 + c] = v;
      s1[j] += v;
      s2[j] += v * v;
    }
  }
#pragma unroll
  for (int off = 8; off >= 1; off >>= 1)
#pragma unroll
    for (int j = 0; j < 4; j++) {
      s1[j] += __shfl_xor(s1[j], off);
      s2[j] += __shfl_xor(s2[j], off);
    }
  if (li == 0) {
#pragma unroll
    for (int j = 0; j < 4; j++) {
      Sm[wid][lg * 4 + j] = s1[j];
      Sv[wid][lg * 4 + j] = s2[j];
    }
  }
  __syncthreads();
  float mean[4], rstd[4];
#pragma unroll
  for (int j = 0; j < 4; j++) {
    int rr = lg * 4 + j;
    float t1 = (Sm[0][rr] + Sm[1][rr]) + (Sm[2][rr] + Sm[3][rr]);
    float t2 = (Sv[0][rr] + Sv[1][rr]) + (Sv[2][rr] + Sv[3][rr]);
    float m = t1 * (1.0f / 384.0f);
    mean[j] = m;
    rstd[j] = rsqrtf(t2 * (1.0f / 384.0f) - m * m + 1e-5f);
  }
#pragma unroll
  for (int n = 0; n < 6; n++) {
    int c = wid * 96 + n * 16 + li;
    float gc = g2[c], bc = b2[c];
#pragma unroll
    for (int j = 0; j < 4; j++) {
      int r = r0 + lg * 4 + j;
      h2[fmoff(r, c, 384)] = f2b((vv[n][j] - mean[j]) * rstd[j] * gc + bc);
    }
  }
}

// ---------------- flash attention: 64 q-rows/block, 2 q-tiles/wave ----------
// R13 body (K-prefetch only, V at top). This round: __launch_bounds__(256,3)
// to cap VGPR at ~170 and lift occupancy 8 -> 12 waves/CU.
__global__ __launch_bounds__(256, 3) void attn_k(const u16* __restrict__ q,
                                                 const u16* __restrict__ k,
                                                 const u16* __restrict__ vt,
                                                 u16* __restrict__ out) {
  __shared__ __align__(16) float Ol[3][2][16][64];
  __shared__ float Ls[3][64];

  int tid = threadIdx.x;
  int lane = tid & 63, wid = tid >> 6;
  int l31 = lane & 31, hi = lane >> 5;
  int bid = blockIdx.x;
  int nid = (bid & 7) * 96 + (bid >> 3);
  int bh = nid >> 5, qT = nid & 31;
  int b = bh / 6, hh = bh - b * 6;
  int qb = qT * 64;

  const u16* qp_ = q + ((size_t)bh * 64 + qT * 2) * 2048 + lane * 8;
  const u16* kp_ = k + ((size_t)bh * 64 + wid * 16) * 2048 + lane * 8;
  const u16* vp_ = vt + ((size_t)bh * 64 + wid * 16) * 2048 + lane * 8;

  uint4 qf0[4], qf1[4], kf[4];
#pragma unroll
  for (int c = 0; c < 4; c++) qf0[c] = *(const uint4*)(qp_ + c * 512);
#pragma unroll
  for (int c = 0; c < 4; c++) qf1[c] = *(const uint4*)(qp_ + 2048 + c * 512);
#pragma unroll
  for (int c = 0; c < 4; c++) kf[c] = *(const uint4*)(kp_ + c * 512);
  kp_ += 2048;

  f32x16 o00, o01, o10, o11;
#pragma unroll
  for (int r = 0; r < 16; r++) {
    o00[r] = 0.f; o01[r] = 0.f; o10[r] = 0.f; o11[r] = 0.f;
  }
  float ls0 = 0.f, ls1 = 0.f;

#pragma unroll
  for (int t = 0; t < 16; t++) {
    uint4 vf0 = *(const uint4*)(vp_);
    uint4 vf1 = *(const uint4*)(vp_ + 512);
    uint4 vf2 = *(const uint4*)(vp_ + 1024);
    uint4 vf3 = *(const uint4*)(vp_ + 1536);
    uint4 kn[4];
    if (t < 15) {
#pragma unroll
      for (int c = 0; c < 4; c++) kn[c] = *(const uint4*)(kp_ + c * 512);
    }

    {
      f32x16 s;
#pragma unroll
      for (int r = 0; r < 16; r++) s[r] = 0.f;
#pragma unroll
      for (int c = 0; c < 4; c++) s = mfma32(kf[c], qf0[c], s);
      float p[16];
#pragma unroll
      for (int r = 0; r < 16; r++) p[r] = __builtin_amdgcn_exp2f(s[r]);
      ls0 += ((p[0] + p[1]) + (p[2] + p[3])) + ((p[4] + p[5]) + (p[6] + p[7])) +
             ((p[8] + p[9]) + (p[10] + p[11])) +
             ((p[12] + p[13]) + (p[14] + p[15]));
      u32 u[8];
#pragma unroll
      for (int i = 0; i < 8; i++) u[i] = pkbf(p[2 * i], p[2 * i + 1]);
      plswap(u[0], u[2]); plswap(u[1], u[3]);
      plswap(u[4], u[6]); plswap(u[5], u[7]);
      uint4 pa0 = {u[0], u[1], u[2], u[3]};
      uint4 pa1 = {u[4], u[5], u[6], u[7]};
      o00 = mfma32(pa0, vf0, o00);
      o00 = mfma32(pa1, vf1, o00);
      o01 = mfma32(pa0, vf2, o01);
      o01 = mfma32(pa1, vf3, o01);
    }
    {
      f32x16 s;
#pragma unroll
      for (int r = 0; r < 16; r++) s[r] = 0.f;
#pragma unroll
      for (int c = 0; c < 4; c++) s = mfma32(kf[c], qf1[c], s);
      float p[16];
#pragma unroll
      for (int r = 0; r < 16; r++) p[r] = __builtin_amdgcn_exp2f(s[r]);
      ls1 += ((p[0] + p[1]) + (p[2] + p[3])) + ((p[4] + p[5]) + (p[6] + p[7])) +
             ((p[8] + p[9]) + (p[10] + p[11])) +
             ((p[12] + p[13]) + (p[14] + p[15]));
      u32 u[8];
#pragma unroll
      for (int i = 0; i < 8; i++) u[i] = pkbf(p[2 * i], p[2 * i + 1]);
      plswap(u[0], u[2]); plswap(u[1], u[3]);
      plswap(u[4], u[6]); plswap(u[5], u[7]);
      uint4 pa0 = {u[0], u[1], u[2], u[3]};
      uint4 pa1 = {u[4], u[5], u[6], u[7]};
      o10 = mfma32(pa0, vf0, o10);
      o10 = mfma32(pa1, vf1, o10);
      o11 = mfma32(pa0, vf2, o11);
      o11 = mfma32(pa1, vf3, o11);
    }

    if (t < 15) {
#pragma unroll
      for (int c = 0; c < 4; c++) kf[c] = kn[c];
    }
    kp_ += 2048;
    vp_ += 2048;
  }

  ls0 += __shfl_xor(ls0, 32);
  ls1 += __shfl_xor(ls1, 32);

  if (wid) {
#pragma unroll
    for (int r = 0; r < 16; r++) {
      Ol[wid - 1][0][r][lane] = o00[r];
      Ol[wid - 1][1][r][lane] = o01[r];
    }
    Ls[wid - 1][lane] = ls0;
  }
  __syncthreads();
  if (wid == 0) {
#pragma unroll
    for (int w = 0; w < 3; w++) ls0 += Ls[w][lane];
#pragma unroll
    for (int r = 0; r < 16; r++)
#pragma unroll
      for (int w = 0; w < 3; w++) {
        o00[r] += Ol[w][0][r][lane];
        o01[r] += Ol[w][1][r][lane];
      }
    float rl = 1.0f / ls0;
#pragma unroll
    for (int r = 0; r < 16; r++) {
      int qo = (r & 3) + 8 * (r >> 2) + hi * 4;
      float rlq = __shfl(rl, qo, 64);
      int row = b * 2048 + qb + qo;
      out[fmoff(row, hh * 64 + l31, 384)] = f2b(o00[r] * rlq);
      out[fmoff(row, hh * 64 + 32 + l31, 384)] = f2b(o01[r] * rlq);
    }
  }
  __syncthreads();
  if (wid) {
#pragma unroll
    for (int r = 0; r < 16; r++) {
      Ol[wid - 1][0][r][lane] = o10[r];
      Ol[wid - 1][1][r][lane] = o11[r];
    }
    Ls[wid - 1][lane] = ls1;
  }
  __syncthreads();
  if (wid == 0) {
#pragma unroll
    for (int w = 0; w < 3; w++) ls1 += Ls[w][lane];
#pragma unroll
    for (int r = 0; r < 16; r++)
#pragma unroll
      for (int w = 0; w < 3; w++) {
        o10[r] += Ol[w][0][r][lane];
        o11[r] += Ol[w][1][r][lane];
      }
    float rl = 1.0f / ls1;
#pragma unroll
    for (int r = 0; r < 16; r++) {
      int qo = (r & 3) + 8 * (r >> 2) + hi * 4;
      float rlq = __shfl(rl, qo, 64);
      int row = b * 2048 + qb + 32 + qo;
      out[fmoff(row, hh * 64 + l31, 384)] = f2b(o10[r] * rlq);
      out[fmoff(row, hh * 64 + 32 + l31, 384)] = f2b(o11[r] * rlq);
    }
  }
}

// ---------------------------------------------------------------------------
extern "C" void kernel_launch(void* const* d_in, const int* in_sizes, int n_in,
                              void* d_out, int out_size, void* d_ws,
                              size_t ws_size, hipStream_t stream) {
  const float* x      = (const float*)d_in[0];
  const float* ln1_g  = (const float*)d_in[1];
  const float* ln1_b  = (const float*)d_in[2];
  const float* qkv_w  = (const float*)d_in[3];
  const float* qkv_b  = (const float*)d_in[4];
  const float* proj_w = (const float*)d_in[5];
  const float* proj_b = (const float*)d_in[6];
  const float* ln2_g  = (const float*)d_in[7];
  const float* ln2_b  = (const float*)d_in[8];
  const float* fc1_w  = (const float*)d_in[9];
  const float* fc1_b  = (const float*)d_in[10];
  const float* fc2_w  = (const float*)d_in[11];
  const float* fc2_b  = (const float*)d_in[12];
  float* out = (float*)d_out;

  char* p = (char*)d_ws;
  u16* qkvwt  = (u16*)p;  p += (size_t)1152 * 384 * 2;
  u16* projwt = (u16*)p;  p += (size_t)384 * 384 * 2;
  u16* fc1wt  = (u16*)p;  p += (size_t)1536 * 384 * 2;
  u16* fc2wt  = (u16*)p;  p += (size_t)384 * 1536 * 2;
  float* x1   = (float*)p; p += (size_t)8192 * 384 * 4;
  u16* reg1   = (u16*)p;  p += (size_t)8192 * 384 * 2;   // h1 -> aout -> h2
  u16* reg2   = (u16*)p;  p += (size_t)8192 * 1536 * 2;  // q,k,vt -> h3
  u16* qd  = reg2;
  u16* kd  = reg2 + (size_t)24 * 2048 * 64;
  u16* vtd = kd + (size_t)24 * 2048 * 64;
  u16* h3  = reg2;

  prep_k<<<432 + 2048, 256, 0, stream>>>(qkv_w, qkvwt, proj_w, projwt,
                                         fc1_w, fc1wt, fc2_w, fc2wt,
                                         x, ln1_g, ln1_b, reg1);
  gemm_k<2, 4, 384, 18, 2><<<dim3(1152), 256, 0, stream>>>(
      reg1, qkvwt, qkv_b, nullptr, nullptr, 1152, qd, kd, vtd);
  attn_k<<<dim3(768), 256, 0, stream>>>(qd, kd, vtd, reg1);
  projln_k<<<dim3(512), 256, 0, stream>>>(reg1, projwt, proj_b, x,
                                          ln2_g, ln2_b, x1, reg1);
  gemm_k<1, 4, 384, 24, 2><<<dim3(1536), 256, 0, stream>>>(
      reg1, fc1wt, fc1_b, nullptr, h3, 1536, nullptr, nullptr, nullptr);
  gemm_k<0, 2, 1536, 6, 4><<<dim3(768), 256, 0, stream>>>(
      h3, fc2wt, fc2_b, x1, out, 384, nullptr, nullptr, nullptr);
}

// Round 19
// 120.844 us; speedup vs baseline: 1.2603x; 1.2603x over previous
//
#include <hip/hip_runtime.h>

typedef unsigned short u16;
typedef unsigned int u32;
typedef __bf16 bf16x8_t __attribute__((ext_vector_type(8)));
typedef float f32x4 __attribute__((ext_vector_type(4)));
typedef float f32x16 __attribute__((ext_vector_type(16)));

__device__ __forceinline__ u16 f2b(float f) {
  union { float f; u32 u; } v; v.f = f;
  u32 r = v.u + 0x7fffu + ((v.u >> 16) & 1u);
  return (u16)(r >> 16);
}

__device__ __forceinline__ u32 pkbf(float a, float b) {
  union { __bf16 h[2]; u32 u; } v;
  v.h[0] = (__bf16)a; v.h[1] = (__bf16)b;
  return v.u;
}

// fragment-major offset for bf16 activation matrices [M rows][Kd cols]:
// 16x8 tiles; a GEMM A-fragment wave-load is 1KB contiguous.
__device__ __forceinline__ size_t fmoff(int r, int c, int Kd) {
  return ((size_t)(r >> 4) * (Kd >> 3) + (c >> 3)) * 128 + (r & 15) * 8 + (c & 7);
}

__device__ __forceinline__ f32x4 mfma16(uint4 a, uint4 b, f32x4 c) {
  return __builtin_amdgcn_mfma_f32_16x16x32_bf16(
      __builtin_bit_cast(bf16x8_t, a), __builtin_bit_cast(bf16x8_t, b), c, 0, 0, 0);
}

__device__ __forceinline__ f32x16 mfma32(uint4 a, uint4 b, f32x16 c) {
  return __builtin_amdgcn_mfma_f32_32x32x16_bf16(
      __builtin_bit_cast(bf16x8_t, a), __builtin_bit_cast(bf16x8_t, b), c, 0, 0, 0);
}

__device__ __forceinline__ void plswap(u32& a, u32& b) {
  asm("v_permlane32_swap_b32 %0, %1" : "+v"(a), "+v"(b));
}

__device__ __forceinline__ void load_lds16(const void* g, void* l) {
  __builtin_amdgcn_global_load_lds(
      (const __attribute__((address_space(1))) unsigned int*)g,
      (__attribute__((address_space(3))) unsigned int*)l, 16, 0, 0);
}

template <int N>
__device__ __forceinline__ void waitvm() {
  if constexpr (N == 0) asm volatile("s_waitcnt vmcnt(0)" ::: "memory");
  else if constexpr (N == 4) asm volatile("s_waitcnt vmcnt(4)" ::: "memory");
  else if constexpr (N == 6) asm volatile("s_waitcnt vmcnt(6)" ::: "memory");
  else if constexpr (N == 8) asm volatile("s_waitcnt vmcnt(8)" ::: "memory");
  else asm volatile("s_waitcnt vmcnt(10)" ::: "memory");
}

// ---------------- LayerNorm row body: 384 f32 -> bf16 fragment-major --------
__device__ __forceinline__ void ln_body(const float* __restrict__ x,
                                        const float* __restrict__ g,
                                        const float* __restrict__ bta,
                                        u16* __restrict__ out, int row,
                                        int lane) {
  const float* xr = x + (size_t)row * 384;
  float v[6];
  float s = 0.f;
#pragma unroll
  for (int i = 0; i < 6; i++) { v[i] = xr[i * 64 + lane]; s += v[i]; }
#pragma unroll
  for (int off = 32; off >= 1; off >>= 1) s += __shfl_xor(s, off);
  float mean = s * (1.0f / 384.0f);
  float vs = 0.f;
#pragma unroll
  for (int i = 0; i < 6; i++) { float d = v[i] - mean; vs += d * d; }
#pragma unroll
  for (int off = 32; off >= 1; off >>= 1) vs += __shfl_xor(vs, off);
  float rstd = rsqrtf(vs * (1.0f / 384.0f) + 1e-5f);
#pragma unroll
  for (int i = 0; i < 6; i++) {
    int c = i * 64 + lane;
    out[fmoff(row, c, 384)] = f2b((v[i] - mean) * rstd * g[c] + bta[c]);
  }
}

__global__ __launch_bounds__(256) void ln_k(const float* __restrict__ x,
                                            const float* __restrict__ g,
                                            const float* __restrict__ bta,
                                            u16* __restrict__ out) {
  ln_body(x, g, bta, out, blockIdx.x * 4 + (threadIdx.x >> 6),
          threadIdx.x & 63);
}

// ---------------- prep: weight transposes (tiles 0..431) + ln1 (rest) -------
__global__ __launch_bounds__(256) void prep_k(
    const float* __restrict__ w0, u16* __restrict__ t0_,
    const float* __restrict__ w1, u16* __restrict__ t1_,
    const float* __restrict__ w2, u16* __restrict__ t2_,
    const float* __restrict__ w3, u16* __restrict__ t3_,
    const float* __restrict__ x, const float* __restrict__ g,
    const float* __restrict__ bta, u16* __restrict__ lnout) {
  __shared__ u16 L[64][68];
  int tile = blockIdx.x, tid = threadIdx.x;
  if (tile >= 432) {
    ln_body(x, g, bta, lnout, (tile - 432) * 4 + (tid >> 6), tid & 63);
    return;
  }
  const float* w; u16* wt; int K, N, rel;
  if (tile < 108)      { w = w0; wt = t0_; K = 384;  N = 1152; rel = tile; }
  else if (tile < 144) { w = w1; wt = t1_; K = 384;  N = 384;  rel = tile - 108; }
  else if (tile < 288) { w = w2; wt = t2_; K = 384;  N = 1536; rel = tile - 144; }
  else                 { w = w3; wt = t3_; K = 1536; N = 384;  rel = tile - 288; }
  int ntx = N >> 6;
  int tk = (rel / ntx) << 6, tn = (rel - (rel / ntx) * ntx) << 6;

  int r = tid >> 2, c0 = (tid & 3) << 4;
  const float* src = w + (size_t)(tk + r) * N + tn + c0;
#pragma unroll
  for (int j = 0; j < 16; j += 4) {
    float4 a = *(const float4*)(src + j);
    L[r][c0 + j + 0] = f2b(a.x);
    L[r][c0 + j + 1] = f2b(a.y);
    L[r][c0 + j + 2] = f2b(a.z);
    L[r][c0 + j + 3] = f2b(a.w);
  }
  __syncthreads();
  int n = tid >> 2, k0 = (tid & 3) << 4;
  u16 tmp[16];
#pragma unroll
  for (int j = 0; j < 16; j++) tmp[j] = L[k0 + j][n];
  u16* dst = wt + (size_t)(tn + n) * K + tk + k0;
  *(uint4*)dst = *(const uint4*)(tmp);
  *(uint4*)(dst + 8) = *(const uint4*)(tmp + 8);
}

// ---------------- GEMM: A fragment-major direct-to-reg, B LDS triple-buffer -
// 1D grid with XCD swizzle: all NX col-blocks of a row-panel land on the
// same XCD (A-panel fetched once per L2). BM = MR*32, BN = 64, BK = 64.
template <int EPI, int MR, int KD, int NX, int MINW>
__global__ __launch_bounds__(256, MINW) void gemm_k(
    const u16* __restrict__ A, const u16* __restrict__ Bt,
    const float* __restrict__ bias, const float* __restrict__ res,
    void* __restrict__ outp, int Nn,
    u16* __restrict__ qp, u16* __restrict__ kp, u16* __restrict__ vtp) {
  constexpr int NS = KD / 64;
  constexpr int KD8 = KD / 8;
  __shared__ __align__(16) u16 Bs[3][64 * 64];
  int tid = threadIdx.x;
  int lane = tid & 63, wid = tid >> 6;
  int li = lane & 15, lg = lane >> 4;
  int wr = wid >> 1, wc = wid & 1;

  int p = blockIdx.x;
  int idx = p >> 3;
  int cx = idx % NX;
  int row0 = ((p & 7) + ((idx / NX) << 3)) * (MR * 32);
  int col0 = cx * 64;

  int lr = lane >> 3;
  int sc8 = ((lane & 7) ^ lr) * 8;    // pre-swizzled B source chunk (u16)

  const u16* Ab = A + ((size_t)(row0 / 16 + wr * MR) * KD8 + lg) * 128 + li * 8;

  f32x4 z = {0.f, 0.f, 0.f, 0.f};
  f32x4 acc[MR][2];
#pragma unroll
  for (int m = 0; m < MR; m++)
#pragma unroll
    for (int n = 0; n < 2; n++) acc[m][n] = z;

  uint4 af0[MR][2], af1[MR][2];

  auto stageB = [&](int buf, int k0) {
#pragma unroll
    for (int j = 0; j < 2; j++) {
      int ib = wid * 2 + j;
      load_lds16(Bt + (size_t)(col0 + ib * 8 + lr) * KD + k0 + sc8,
                 (char*)Bs[buf] + ib * 1024);
    }
  };
  auto loadA = [&](uint4 (*dst)[2], int t) {
#pragma unroll
    for (int m = 0; m < MR; m++)
#pragma unroll
      for (int kk = 0; kk < 2; kk++)
        dst[m][kk] =
            *(const uint4*)(Ab + ((size_t)m * KD8 + t * 8 + kk * 4) * 128);
  };

  stageB(0, 0);
  stageB(1, 64);
  loadA(af0, 0);
  if (NS > 1) loadA(af1, 1);
  waitvm<2 * MR>();   // B0,B1,A0 done; A1 in flight
  __builtin_amdgcn_s_barrier();
  asm volatile("" ::: "memory");

#pragma unroll
  for (int t = 0; t < NS; t++) {
    if (t + 2 < NS) stageB((t + 2) % 3, (t + 2) * 64);
    const char* Bsb = (const char*)Bs[t % 3];
#pragma unroll
    for (int kk = 0; kk < 2; kk++) {
      uint4 bf[2];
#pragma unroll
      for (int n = 0; n < 2; n++) {
        int c = wc * 32 + n * 16 + li;
        bf[n] = *(const uint4*)(Bsb + c * 128 +
                                ((kk * 64 + lg * 16) ^ ((c & 7) << 4)));
      }
#pragma unroll
      for (int m = 0; m < MR; m++)
#pragma unroll
        for (int n = 0; n < 2; n++)
          acc[m][n] = mfma16((t & 1) ? af1[m][kk] : af0[m][kk], bf[n],
                             acc[m][n]);
    }
    if (t + 2 < NS) {
      if (t & 1) loadA(af1, t + 2);
      else       loadA(af0, t + 2);
      waitvm<2 + 2 * MR>();   // (t+1)'s B and A landed; (t+2) in flight
      __builtin_amdgcn_s_barrier();
      asm volatile("" ::: "memory");
    } else if (t + 1 < NS) {
      waitvm<0>();
      __builtin_amdgcn_s_barrier();
      asm volatile("" ::: "memory");
    }
  }

#pragma unroll
  for (int m = 0; m < MR; m++) {
#pragma unroll
    for (int n = 0; n < 2; n++) {
#pragma unroll
      for (int j = 0; j < 4; j++) {
        int r = row0 + wr * (MR * 16) + m * 16 + lg * 4 + j;
        int c = col0 + wc * 32 + n * 16 + li;
        float v = acc[m][n][j] + bias[c];
        if (EPI == 0) {
          ((float*)outp)[(size_t)r * Nn + c] = v + res[(size_t)r * Nn + c];
        } else if (EPI == 1) {
          float e = __expf(-1.5957691f * v * (1.f + 0.044715f * v * v));
          ((u16*)outp)[fmoff(r, c, Nn)] = f2b(v / (1.f + e));
        } else {
          int tt = c / 384;
          int c2 = c - tt * 384;
          int hh = c2 >> 6, d = c2 & 63;
          int bb = r >> 11, nn = r & 2047;
          size_t bh = (size_t)bb * 6 + hh;
          int tile = nn >> 5;
          if (tt == 2) {
            int kvl = nn & 31;
            int kvHalf = (kvl >> 4) & 1, h2 = (kvl >> 3) & 1, jj = kvl & 7;
            int dTile = d >> 5, l31 = d & 31;
            vtp[(((bh * 64 + tile) * 2 + dTile) * 2 + kvHalf) * 512 +
                (l31 + h2 * 32) * 8 + jj] = f2b(v);
          } else {
            int chunk = d >> 4, h2 = (d >> 3) & 1, e = d & 7;
            int l31 = nn & 31;
            size_t off = ((bh * 64 + tile) * 4 + chunk) * 512 +
                         (l31 + h2 * 32) * 8 + e;
            if (tt == 0) qp[off] = f2b(v * 0.18033688f);  // 0.125 * log2(e)
            else         kp[off] = f2b(v);
          }
        }
      }
    }
  }
}

// ---------------- flash attention: 64 q-rows/block, 2 q-tiles/wave ----------
// q/k/vt fragment-major; q pre-scaled by 0.125*log2e so P = exp2(S).
// 4 waves = 4 kv-quarters; K prefetched one tile ahead, V loaded at top;
// K/V registers shared by both q-tiles. (R13 body, proven 120.4 config.)
__global__ __launch_bounds__(256, 2) void attn_k(const u16* __restrict__ q,
                                                 const u16* __restrict__ k,
                                                 const u16* __restrict__ vt,
                                                 u16* __restrict__ out) {
  __shared__ __align__(16) float Ol[3][2][16][64];  // 24 KB, reused per tile
  __shared__ float Ls[3][64];

  int tid = threadIdx.x;
  int lane = tid & 63, wid = tid >> 6;
  int l31 = lane & 31, hi = lane >> 5;
  int bid = blockIdx.x;
  int nid = (bid & 7) * 96 + (bid >> 3);   // XCD swizzle: 768 = 8 XCD * 96
  int bh = nid >> 5, qT = nid & 31;
  int b = bh / 6, hh = bh - b * 6;
  int qb = qT * 64;

  const u16* qp_ = q + ((size_t)bh * 64 + qT * 2) * 2048 + lane * 8;
  const u16* kp_ = k + ((size_t)bh * 64 + wid * 16) * 2048 + lane * 8;
  const u16* vp_ = vt + ((size_t)bh * 64 + wid * 16) * 2048 + lane * 8;

  uint4 qf0[4], qf1[4], kf[4];
#pragma unroll
  for (int c = 0; c < 4; c++) qf0[c] = *(const uint4*)(qp_ + c * 512);
#pragma unroll
  for (int c = 0; c < 4; c++) qf1[c] = *(const uint4*)(qp_ + 2048 + c * 512);
#pragma unroll
  for (int c = 0; c < 4; c++) kf[c] = *(const uint4*)(kp_ + c * 512);
  kp_ += 2048;

  f32x16 o00, o01, o10, o11;
#pragma unroll
  for (int r = 0; r < 16; r++) {
    o00[r] = 0.f; o01[r] = 0.f; o10[r] = 0.f; o11[r] = 0.f;
  }
  float ls0 = 0.f, ls1 = 0.f;

#pragma unroll
  for (int t = 0; t < 16; t++) {
    // V fragments for this tile (shared by both q-tiles)
    uint4 vf0 = *(const uint4*)(vp_);
    uint4 vf1 = *(const uint4*)(vp_ + 512);
    uint4 vf2 = *(const uint4*)(vp_ + 1024);
    uint4 vf3 = *(const uint4*)(vp_ + 1536);
    // prefetch next tile's K
    uint4 kn[4];
    if (t < 15) {
#pragma unroll
      for (int c = 0; c < 4; c++) kn[c] = *(const uint4*)(kp_ + c * 512);
    }

    // ---- q-tile 0: QK^T, exp2, pack, PV ----
    {
      f32x16 s;
#pragma unroll
      for (int r = 0; r < 16; r++) s[r] = 0.f;
#pragma unroll
      for (int c = 0; c < 4; c++) s = mfma32(kf[c], qf0[c], s);
      float p[16];
#pragma unroll
      for (int r = 0; r < 16; r++) p[r] = __builtin_amdgcn_exp2f(s[r]);
      ls0 += ((p[0] + p[1]) + (p[2] + p[3])) + ((p[4] + p[5]) + (p[6] + p[7])) +
             ((p[8] + p[9]) + (p[10] + p[11])) +
             ((p[12] + p[13]) + (p[14] + p[15]));
      u32 u[8];
#pragma unroll
      for (int i = 0; i < 8; i++) u[i] = pkbf(p[2 * i], p[2 * i + 1]);
      plswap(u[0], u[2]); plswap(u[1], u[3]);
      plswap(u[4], u[6]); plswap(u[5], u[7]);
      uint4 pa0 = {u[0], u[1], u[2], u[3]};
      uint4 pa1 = {u[4], u[5], u[6], u[7]};
      o00 = mfma32(pa0, vf0, o00);
      o00 = mfma32(pa1, vf1, o00);
      o01 = mfma32(pa0, vf2, o01);
      o01 = mfma32(pa1, vf3, o01);
    }
    // ---- q-tile 1 ----
    {
      f32x16 s;
#pragma unroll
      for (int r = 0; r < 16; r++) s[r] = 0.f;
#pragma unroll
      for (int c = 0; c < 4; c++) s = mfma32(kf[c], qf1[c], s);
      float p[16];
#pragma unroll
      for (int r = 0; r < 16; r++) p[r] = __builtin_amdgcn_exp2f(s[r]);
      ls1 += ((p[0] + p[1]) + (p[2] + p[3])) + ((p[4] + p[5]) + (p[6] + p[7])) +
             ((p[8] + p[9]) + (p[10] + p[11])) +
             ((p[12] + p[13]) + (p[14] + p[15]));
      u32 u[8];
#pragma unroll
      for (int i = 0; i < 8; i++) u[i] = pkbf(p[2 * i], p[2 * i + 1]);
      plswap(u[0], u[2]); plswap(u[1], u[3]);
      plswap(u[4], u[6]); plswap(u[5], u[7]);
      uint4 pa0 = {u[0], u[1], u[2], u[3]};
      uint4 pa1 = {u[4], u[5], u[6], u[7]};
      o10 = mfma32(pa0, vf0, o10);
      o10 = mfma32(pa1, vf1, o10);
      o11 = mfma32(pa0, vf2, o11);
      o11 = mfma32(pa1, vf3, o11);
    }

    if (t < 15) {
#pragma unroll
      for (int c = 0; c < 4; c++) kf[c] = kn[c];
    }
    kp_ += 2048;
    vp_ += 2048;
  }

  ls0 += __shfl_xor(ls0, 32);
  ls1 += __shfl_xor(ls1, 32);

  // ---- combine, q-tile 0 ----
  if (wid) {
#pragma unroll
    for (int r = 0; r < 16; r++) {
      Ol[wid - 1][0][r][lane] = o00[r];
      Ol[wid - 1][1][r][lane] = o01[r];
    }
    Ls[wid - 1][lane] = ls0;
  }
  __syncthreads();
  if (wid == 0) {
#pragma unroll
    for (int w = 0; w < 3; w++) ls0 += Ls[w][lane];
#pragma unroll
    for (int r = 0; r < 16; r++)
#pragma unroll
      for (int w = 0; w < 3; w++) {
        o00[r] += Ol[w][0][r][lane];
        o01[r] += Ol[w][1][r][lane];
      }
    float rl = 1.0f / ls0;
#pragma unroll
    for (int r = 0; r < 16; r++) {
      int qo = (r & 3) + 8 * (r >> 2) + hi * 4;
      float rlq = __shfl(rl, qo, 64);
      int row = b * 2048 + qb + qo;
      out[fmoff(row, hh * 64 + l31, 384)] = f2b(o00[r] * rlq);
      out[fmoff(row, hh * 64 + 32 + l31, 384)] = f2b(o01[r] * rlq);
    }
  }
  __syncthreads();
  // ---- combine, q-tile 1 ----
  if (wid) {
#pragma unroll
    for (int r = 0; r < 16; r++) {
      Ol[wid - 1][0][r][lane] = o10[r];
      Ol[wid - 1][1][r][lane] = o11[r];
    }
    Ls[wid - 1][lane] = ls1;
  }
  __syncthreads();
  if (wid == 0) {
#pragma unroll
    for (int w = 0; w < 3; w++) ls1 += Ls[w][lane];
#pragma unroll
    for (int r = 0; r < 16; r++)
#pragma unroll
      for (int w = 0; w < 3; w++) {
        o10[r] += Ol[w][0][r][lane];
        o11[r] += Ol[w][1][r][lane];
      }
    float rl = 1.0f / ls1;
#pragma unroll
    for (int r = 0; r < 16; r++) {
      int qo = (r & 3) + 8 * (r >> 2) + hi * 4;
      float rlq = __shfl(rl, qo, 64);
      int row = b * 2048 + qb + 32 + qo;
      out[fmoff(row, hh * 64 + l31, 384)] = f2b(o10[r] * rlq);
      out[fmoff(row, hh * 64 + 32 + l31, 384)] = f2b(o11[r] * rlq);
    }
  }
}

// ---------------------------------------------------------------------------
extern "C" void kernel_launch(void* const* d_in, const int* in_sizes, int n_in,
                              void* d_out, int out_size, void* d_ws,
                              size_t ws_size, hipStream_t stream) {
  const float* x      = (const float*)d_in[0];
  const float* ln1_g  = (const float*)d_in[1];
  const float* ln1_b  = (const float*)d_in[2];
  const float* qkv_w  = (const float*)d_in[3];
  const float* qkv_b  = (const float*)d_in[4];
  const float* proj_w = (const float*)d_in[5];
  const float* proj_b = (const float*)d_in[6];
  const float* ln2_g  = (const float*)d_in[7];
  const float* ln2_b  = (const float*)d_in[8];
  const float* fc1_w  = (const float*)d_in[9];
  const float* fc1_b  = (const float*)d_in[10];
  const float* fc2_w  = (const float*)d_in[11];
  const float* fc2_b  = (const float*)d_in[12];
  float* out = (float*)d_out;

  char* p = (char*)d_ws;
  u16* qkvwt  = (u16*)p;  p += (size_t)1152 * 384 * 2;
  u16* projwt = (u16*)p;  p += (size_t)384 * 384 * 2;
  u16* fc1wt  = (u16*)p;  p += (size_t)1536 * 384 * 2;
  u16* fc2wt  = (u16*)p;  p += (size_t)384 * 1536 * 2;
  float* x1   = (float*)p; p += (size_t)8192 * 384 * 4;
  u16* reg1   = (u16*)p;  p += (size_t)8192 * 384 * 2;   // h1 -> aout -> h2
  u16* reg2   = (u16*)p;  p += (size_t)8192 * 1536 * 2;  // q,k,vt -> h3
  u16* qd  = reg2;
  u16* kd  = reg2 + (size_t)24 * 2048 * 64;
  u16* vtd = kd + (size_t)24 * 2048 * 64;
  u16* h3  = reg2;

  prep_k<<<432 + 2048, 256, 0, stream>>>(qkv_w, qkvwt, proj_w, projwt,
                                         fc1_w, fc1wt, fc2_w, fc2wt,
                                         x, ln1_g, ln1_b, reg1);
  gemm_k<2, 4, 384, 18, 2><<<dim3(1152), 256, 0, stream>>>(
      reg1, qkvwt, qkv_b, nullptr, nullptr, 1152, qd, kd, vtd);
  attn_k<<<dim3(768), 256, 0, stream>>>(qd, kd, vtd, reg1);
  gemm_k<0, 2, 384, 6, 4><<<dim3(768), 256, 0, stream>>>(
      reg1, projwt, proj_b, x, x1, 384, nullptr, nullptr, nullptr);
  ln_k<<<2048, 256, 0, stream>>>(x1, ln2_g, ln2_b, reg1);
  gemm_k<1, 4, 384, 24, 2><<<dim3(1536), 256, 0, stream>>>(
      reg1, fc1wt, fc1_b, nullptr, h3, 1536, nullptr, nullptr, nullptr);
  gemm_k<0, 2, 1536, 6, 4><<<dim3(768), 256, 0, stream>>>(
      h3, fc2wt, fc2_b, x1, out, 384, nullptr, nullptr, nullptr);
}

// Round 20
// 120.090 us; speedup vs baseline: 1.2682x; 1.0063x over previous
//
#include <hip/hip_runtime.h>

typedef unsigned short u16;
typedef unsigned int u32;
typedef __bf16 bf16x8_t __attribute__((ext_vector_type(8)));
typedef float f32x4 __attribute__((ext_vector_type(4)));
typedef float f32x16 __attribute__((ext_vector_type(16)));

__device__ __forceinline__ u16 f2b(float f) {
  union { float f; u32 u; } v; v.f = f;
  u32 r = v.u + 0x7fffu + ((v.u >> 16) & 1u);
  return (u16)(r >> 16);
}

__device__ __forceinline__ u32 pkbf(float a, float b) {
  union { __bf16 h[2]; u32 u; } v;
  v.h[0] = (__bf16)a; v.h[1] = (__bf16)b;
  return v.u;
}

// fragment-major offset for bf16 activation matrices [M rows][Kd cols]:
// 16x8 tiles; a GEMM A-fragment wave-load is 1KB contiguous.
__device__ __forceinline__ size_t fmoff(int r, int c, int Kd) {
  return ((size_t)(r >> 4) * (Kd >> 3) + (c >> 3)) * 128 + (r & 15) * 8 + (c & 7);
}

__device__ __forceinline__ f32x4 mfma16(uint4 a, uint4 b, f32x4 c) {
  return __builtin_amdgcn_mfma_f32_16x16x32_bf16(
      __builtin_bit_cast(bf16x8_t, a), __builtin_bit_cast(bf16x8_t, b), c, 0, 0, 0);
}

__device__ __forceinline__ f32x16 mfma32(uint4 a, uint4 b, f32x16 c) {
  return __builtin_amdgcn_mfma_f32_32x32x16_bf16(
      __builtin_bit_cast(bf16x8_t, a), __builtin_bit_cast(bf16x8_t, b), c, 0, 0, 0);
}

__device__ __forceinline__ void plswap(u32& a, u32& b) {
  asm("v_permlane32_swap_b32 %0, %1" : "+v"(a), "+v"(b));
}

__device__ __forceinline__ void load_lds16(const void* g, void* l) {
  __builtin_amdgcn_global_load_lds(
      (const __attribute__((address_space(1))) unsigned int*)g,
      (__attribute__((address_space(3))) unsigned int*)l, 16, 0, 0);
}

template <int N>
__device__ __forceinline__ void waitvm() {
  if constexpr (N == 0) asm volatile("s_waitcnt vmcnt(0)" ::: "memory");
  else if constexpr (N == 4) asm volatile("s_waitcnt vmcnt(4)" ::: "memory");
  else if constexpr (N == 6) asm volatile("s_waitcnt vmcnt(6)" ::: "memory");
  else if constexpr (N == 8) asm volatile("s_waitcnt vmcnt(8)" ::: "memory");
  else asm volatile("s_waitcnt vmcnt(10)" ::: "memory");
}

// ---------------- LayerNorm row body: 384 f32 -> bf16 fragment-major --------
__device__ __forceinline__ void ln_body(const float* __restrict__ x,
                                        const float* __restrict__ g,
                                        const float* __restrict__ bta,
                                        u16* __restrict__ out, int row,
                                        int lane) {
  const float* xr = x + (size_t)row * 384;
  float v[6];
  float s = 0.f;
#pragma unroll
  for (int i = 0; i < 6; i++) { v[i] = xr[i * 64 + lane]; s += v[i]; }
#pragma unroll
  for (int off = 32; off >= 1; off >>= 1) s += __shfl_xor(s, off);
  float mean = s * (1.0f / 384.0f);
  float vs = 0.f;
#pragma unroll
  for (int i = 0; i < 6; i++) { float d = v[i] - mean; vs += d * d; }
#pragma unroll
  for (int off = 32; off >= 1; off >>= 1) vs += __shfl_xor(vs, off);
  float rstd = rsqrtf(vs * (1.0f / 384.0f) + 1e-5f);
#pragma unroll
  for (int i = 0; i < 6; i++) {
    int c = i * 64 + lane;
    out[fmoff(row, c, 384)] = f2b((v[i] - mean) * rstd * g[c] + bta[c]);
  }
}

__global__ __launch_bounds__(256) void ln_k(const float* __restrict__ x,
                                            const float* __restrict__ g,
                                            const float* __restrict__ bta,
                                            u16* __restrict__ out) {
  ln_body(x, g, bta, out, blockIdx.x * 4 + (threadIdx.x >> 6),
          threadIdx.x & 63);
}

// ---------------- prep: weight transposes (tiles 0..431) + ln1 (rest) -------
__global__ __launch_bounds__(256) void prep_k(
    const float* __restrict__ w0, u16* __restrict__ t0_,
    const float* __restrict__ w1, u16* __restrict__ t1_,
    const float* __restrict__ w2, u16* __restrict__ t2_,
    const float* __restrict__ w3, u16* __restrict__ t3_,
    const float* __restrict__ x, const float* __restrict__ g,
    const float* __restrict__ bta, u16* __restrict__ lnout) {
  __shared__ u16 L[64][68];
  int tile = blockIdx.x, tid = threadIdx.x;
  if (tile >= 432) {
    ln_body(x, g, bta, lnout, (tile - 432) * 4 + (tid >> 6), tid & 63);
    return;
  }
  const float* w; u16* wt; int K, N, rel;
  if (tile < 108)      { w = w0; wt = t0_; K = 384;  N = 1152; rel = tile; }
  else if (tile < 144) { w = w1; wt = t1_; K = 384;  N = 384;  rel = tile - 108; }
  else if (tile < 288) { w = w2; wt = t2_; K = 384;  N = 1536; rel = tile - 144; }
  else                 { w = w3; wt = t3_; K = 1536; N = 384;  rel = tile - 288; }
  int ntx = N >> 6;
  int tk = (rel / ntx) << 6, tn = (rel - (rel / ntx) * ntx) << 6;

  int r = tid >> 2, c0 = (tid & 3) << 4;
  const float* src = w + (size_t)(tk + r) * N + tn + c0;
#pragma unroll
  for (int j = 0; j < 16; j += 4) {
    float4 a = *(const float4*)(src + j);
    L[r][c0 + j + 0] = f2b(a.x);
    L[r][c0 + j + 1] = f2b(a.y);
    L[r][c0 + j + 2] = f2b(a.z);
    L[r][c0 + j + 3] = f2b(a.w);
  }
  __syncthreads();
  int n = tid >> 2, k0 = (tid & 3) << 4;
  u16 tmp[16];
#pragma unroll
  for (int j = 0; j < 16; j++) tmp[j] = L[k0 + j][n];
  u16* dst = wt + (size_t)(tn + n) * K + tk + k0;
  *(uint4*)dst = *(const uint4*)(tmp);
  *(uint4*)(dst + 8) = *(const uint4*)(tmp + 8);
}

// ---------------- GEMM: A fragment-major direct-to-reg, B LDS triple-buffer -
// 1D grid with XCD swizzle: all NX col-blocks of a row-panel land on the
// same XCD (A-panel fetched once per L2). BM = MR*32, BN = 64, BK = 64.
template <int EPI, int MR, int KD, int NX, int MINW>
__global__ __launch_bounds__(256, MINW) void gemm_k(
    const u16* __restrict__ A, const u16* __restrict__ Bt,
    const float* __restrict__ bias, const float* __restrict__ res,
    void* __restrict__ outp, int Nn,
    u16* __restrict__ qp, u16* __restrict__ kp, u16* __restrict__ vtp) {
  constexpr int NS = KD / 64;
  constexpr int KD8 = KD / 8;
  __shared__ __align__(16) u16 Bs[3][64 * 64];
  int tid = threadIdx.x;
  int lane = tid & 63, wid = tid >> 6;
  int li = lane & 15, lg = lane >> 4;
  int wr = wid >> 1, wc = wid & 1;

  int p = blockIdx.x;
  int idx = p >> 3;
  int cx = idx % NX;
  int row0 = ((p & 7) + ((idx / NX) << 3)) * (MR * 32);
  int col0 = cx * 64;

  int lr = lane >> 3;
  int sc8 = ((lane & 7) ^ lr) * 8;    // pre-swizzled B source chunk (u16)

  const u16* Ab = A + ((size_t)(row0 / 16 + wr * MR) * KD8 + lg) * 128 + li * 8;

  f32x4 z = {0.f, 0.f, 0.f, 0.f};
  f32x4 acc[MR][2];
#pragma unroll
  for (int m = 0; m < MR; m++)
#pragma unroll
    for (int n = 0; n < 2; n++) acc[m][n] = z;

  uint4 af0[MR][2], af1[MR][2];

  auto stageB = [&](int buf, int k0) {
#pragma unroll
    for (int j = 0; j < 2; j++) {
      int ib = wid * 2 + j;
      load_lds16(Bt + (size_t)(col0 + ib * 8 + lr) * KD + k0 + sc8,
                 (char*)Bs[buf] + ib * 1024);
    }
  };
  auto loadA = [&](uint4 (*dst)[2], int t) {
#pragma unroll
    for (int m = 0; m < MR; m++)
#pragma unroll
      for (int kk = 0; kk < 2; kk++)
        dst[m][kk] =
            *(const uint4*)(Ab + ((size_t)m * KD8 + t * 8 + kk * 4) * 128);
  };

  stageB(0, 0);
  stageB(1, 64);
  loadA(af0, 0);
  if (NS > 1) loadA(af1, 1);
  waitvm<2 * MR>();   // B0,B1,A0 done; A1 in flight
  __builtin_amdgcn_s_barrier();
  asm volatile("" ::: "memory");

#pragma unroll
  for (int t = 0; t < NS; t++) {
    if (t + 2 < NS) stageB((t + 2) % 3, (t + 2) * 64);
    const char* Bsb = (const char*)Bs[t % 3];
#pragma unroll
    for (int kk = 0; kk < 2; kk++) {
      uint4 bf[2];
#pragma unroll
      for (int n = 0; n < 2; n++) {
        int c = wc * 32 + n * 16 + li;
        bf[n] = *(const uint4*)(Bsb + c * 128 +
                                ((kk * 64 + lg * 16) ^ ((c & 7) << 4)));
      }
#pragma unroll
      for (int m = 0; m < MR; m++)
#pragma unroll
        for (int n = 0; n < 2; n++)
          acc[m][n] = mfma16((t & 1) ? af1[m][kk] : af0[m][kk], bf[n],
                             acc[m][n]);
    }
    if (t + 2 < NS) {
      if (t & 1) loadA(af1, t + 2);
      else       loadA(af0, t + 2);
      waitvm<2 + 2 * MR>();   // (t+1)'s B and A landed; (t+2) in flight
      __builtin_amdgcn_s_barrier();
      asm volatile("" ::: "memory");
    } else if (t + 1 < NS) {
      waitvm<0>();
      __builtin_amdgcn_s_barrier();
      asm volatile("" ::: "memory");
    }
  }

#pragma unroll
  for (int m = 0; m < MR; m++) {
#pragma unroll
    for (int n = 0; n < 2; n++) {
#pragma unroll
      for (int j = 0; j < 4; j++) {
        int r = row0 + wr * (MR * 16) + m * 16 + lg * 4 + j;
        int c = col0 + wc * 32 + n * 16 + li;
        float v = acc[m][n][j] + bias[c];
        if (EPI == 0) {
          ((float*)outp)[(size_t)r * Nn + c] = v + res[(size_t)r * Nn + c];
        } else if (EPI == 1) {
          float e = __expf(-1.5957691f * v * (1.f + 0.044715f * v * v));
          ((u16*)outp)[fmoff(r, c, Nn)] = f2b(v / (1.f + e));
        } else {
          int tt = c / 384;
          int c2 = c - tt * 384;
          int hh = c2 >> 6, d = c2 & 63;
          int bb = r >> 11, nn = r & 2047;
          size_t bh = (size_t)bb * 6 + hh;
          int tile = nn >> 5;
          if (tt == 2) {
            int kvl = nn & 31;
            int kvHalf = (kvl >> 4) & 1, h2 = (kvl >> 3) & 1, jj = kvl & 7;
            int dTile = d >> 5, l31 = d & 31;
            vtp[(((bh * 64 + tile) * 2 + dTile) * 2 + kvHalf) * 512 +
                (l31 + h2 * 32) * 8 + jj] = f2b(v);
          } else {
            int chunk = d >> 4, h2 = (d >> 3) & 1, e = d & 7;
            int l31 = nn & 31;
            size_t off = ((bh * 64 + tile) * 4 + chunk) * 512 +
                         (l31 + h2 * 32) * 8 + e;
            if (tt == 0) qp[off] = f2b(v * 0.18033688f);  // 0.125 * log2(e)
            else         kp[off] = f2b(v);
          }
        }
      }
    }
  }
}

// ---------------- flash attention: 64 q-rows/block, 2 q-tiles/wave ----------
// q/k/vt fragment-major; q pre-scaled by 0.125*log2e so P = exp2(S).
// 4 waves = 4 kv-quarters; K prefetched one tile ahead, V loaded at top;
// K/V registers shared by both q-tiles. (R13 body, proven 120.4 config.)
__global__ __launch_bounds__(256, 2) void attn_k(const u16* __restrict__ q,
                                                 const u16* __restrict__ k,
                                                 const u16* __restrict__ vt,
                                                 u16* __restrict__ out) {
  __shared__ __align__(16) float Ol[3][2][16][64];  // 24 KB, reused per tile
  __shared__ float Ls[3][64];

  int tid = threadIdx.x;
  int lane = tid & 63, wid = tid >> 6;
  int l31 = lane & 31, hi = lane >> 5;
  int bid = blockIdx.x;
  int nid = (bid & 7) * 96 + (bid >> 3);   // XCD swizzle: 768 = 8 XCD * 96
  int bh = nid >> 5, qT = nid & 31;
  int b = bh / 6, hh = bh - b * 6;
  int qb = qT * 64;

  const u16* qp_ = q + ((size_t)bh * 64 + qT * 2) * 2048 + lane * 8;
  const u16* kp_ = k + ((size_t)bh * 64 + wid * 16) * 2048 + lane * 8;
  const u16* vp_ = vt + ((size_t)bh * 64 + wid * 16) * 2048 + lane * 8;

  uint4 qf0[4], qf1[4], kf[4];
#pragma unroll
  for (int c = 0; c < 4; c++) qf0[c] = *(const uint4*)(qp_ + c * 512);
#pragma unroll
  for (int c = 0; c < 4; c++) qf1[c] = *(const uint4*)(qp_ + 2048 + c * 512);
#pragma unroll
  for (int c = 0; c < 4; c++) kf[c] = *(const uint4*)(kp_ + c * 512);
  kp_ += 2048;

  f32x16 o00, o01, o10, o11;
#pragma unroll
  for (int r = 0; r < 16; r++) {
    o00[r] = 0.f; o01[r] = 0.f; o10[r] = 0.f; o11[r] = 0.f;
  }
  float ls0 = 0.f, ls1 = 0.f;

#pragma unroll
  for (int t = 0; t < 16; t++) {
    // V fragments for this tile (shared by both q-tiles)
    uint4 vf0 = *(const uint4*)(vp_);
    uint4 vf1 = *(const uint4*)(vp_ + 512);
    uint4 vf2 = *(const uint4*)(vp_ + 1024);
    uint4 vf3 = *(const uint4*)(vp_ + 1536);
    // prefetch next tile's K
    uint4 kn[4];
    if (t < 15) {
#pragma unroll
      for (int c = 0; c < 4; c++) kn[c] = *(const uint4*)(kp_ + c * 512);
    }

    // ---- q-tile 0: QK^T, exp2, pack, PV ----
    {
      f32x16 s;
#pragma unroll
      for (int r = 0; r < 16; r++) s[r] = 0.f;
#pragma unroll
      for (int c = 0; c < 4; c++) s = mfma32(kf[c], qf0[c], s);
      float p[16];
#pragma unroll
      for (int r = 0; r < 16; r++) p[r] = __builtin_amdgcn_exp2f(s[r]);
      ls0 += ((p[0] + p[1]) + (p[2] + p[3])) + ((p[4] + p[5]) + (p[6] + p[7])) +
             ((p[8] + p[9]) + (p[10] + p[11])) +
             ((p[12] + p[13]) + (p[14] + p[15]));
      u32 u[8];
#pragma unroll
      for (int i = 0; i < 8; i++) u[i] = pkbf(p[2 * i], p[2 * i + 1]);
      plswap(u[0], u[2]); plswap(u[1], u[3]);
      plswap(u[4], u[6]); plswap(u[5], u[7]);
      uint4 pa0 = {u[0], u[1], u[2], u[3]};
      uint4 pa1 = {u[4], u[5], u[6], u[7]};
      o00 = mfma32(pa0, vf0, o00);
      o00 = mfma32(pa1, vf1, o00);
      o01 = mfma32(pa0, vf2, o01);
      o01 = mfma32(pa1, vf3, o01);
    }
    // ---- q-tile 1 ----
    {
      f32x16 s;
#pragma unroll
      for (int r = 0; r < 16; r++) s[r] = 0.f;
#pragma unroll
      for (int c = 0; c < 4; c++) s = mfma32(kf[c], qf1[c], s);
      float p[16];
#pragma unroll
      for (int r = 0; r < 16; r++) p[r] = __builtin_amdgcn_exp2f(s[r]);
      ls1 += ((p[0] + p[1]) + (p[2] + p[3])) + ((p[4] + p[5]) + (p[6] + p[7])) +
             ((p[8] + p[9]) + (p[10] + p[11])) +
             ((p[12] + p[13]) + (p[14] + p[15]));
      u32 u[8];
#pragma unroll
      for (int i = 0; i < 8; i++) u[i] = pkbf(p[2 * i], p[2 * i + 1]);
      plswap(u[0], u[2]); plswap(u[1], u[3]);
      plswap(u[4], u[6]); plswap(u[5], u[7]);
      uint4 pa0 = {u[0], u[1], u[2], u[3]};
      uint4 pa1 = {u[4], u[5], u[6], u[7]};
      o10 = mfma32(pa0, vf0, o10);
      o10 = mfma32(pa1, vf1, o10);
      o11 = mfma32(pa0, vf2, o11);
      o11 = mfma32(pa1, vf3, o11);
    }

    if (t < 15) {
#pragma unroll
      for (int c = 0; c < 4; c++) kf[c] = kn[c];
    }
    kp_ += 2048;
    vp_ += 2048;
  }

  ls0 += __shfl_xor(ls0, 32);
  ls1 += __shfl_xor(ls1, 32);

  // ---- combine, q-tile 0 ----
  if (wid) {
#pragma unroll
    for (int r = 0; r < 16; r++) {
      Ol[wid - 1][0][r][lane] = o00[r];
      Ol[wid - 1][1][r][lane] = o01[r];
    }
    Ls[wid - 1][lane] = ls0;
  }
  __syncthreads();
  if (wid == 0) {
#pragma unroll
    for (int w = 0; w < 3; w++) ls0 += Ls[w][lane];
#pragma unroll
    for (int r = 0; r < 16; r++)
#pragma unroll
      for (int w = 0; w < 3; w++) {
        o00[r] += Ol[w][0][r][lane];
        o01[r] += Ol[w][1][r][lane];
      }
    float rl = 1.0f / ls0;
#pragma unroll
    for (int r = 0; r < 16; r++) {
      int qo = (r & 3) + 8 * (r >> 2) + hi * 4;
      float rlq = __shfl(rl, qo, 64);
      int row = b * 2048 + qb + qo;
      out[fmoff(row, hh * 64 + l31, 384)] = f2b(o00[r] * rlq);
      out[fmoff(row, hh * 64 + 32 + l31, 384)] = f2b(o01[r] * rlq);
    }
  }
  __syncthreads();
  // ---- combine, q-tile 1 ----
  if (wid) {
#pragma unroll
    for (int r = 0; r < 16; r++) {
      Ol[wid - 1][0][r][lane] = o10[r];
      Ol[wid - 1][1][r][lane] = o11[r];
    }
    Ls[wid - 1][lane] = ls1;
  }
  __syncthreads();
  if (wid == 0) {
#pragma unroll
    for (int w = 0; w < 3; w++) ls1 += Ls[w][lane];
#pragma unroll
    for (int r = 0; r < 16; r++)
#pragma unroll
      for (int w = 0; w < 3; w++) {
        o10[r] += Ol[w][0][r][lane];
        o11[r] += Ol[w][1][r][lane];
      }
    float rl = 1.0f / ls1;
#pragma unroll
    for (int r = 0; r < 16; r++) {
      int qo = (r & 3) + 8 * (r >> 2) + hi * 4;
      float rlq = __shfl(rl, qo, 64);
      int row = b * 2048 + qb + 32 + qo;
      out[fmoff(row, hh * 64 + l31, 384)] = f2b(o10[r] * rlq);
      out[fmoff(row, hh * 64 + 32 + l31, 384)] = f2b(o11[r] * rlq);
    }
  }
}

// ---------------------------------------------------------------------------
extern "C" void kernel_launch(void* const* d_in, const int* in_sizes, int n_in,
                              void* d_out, int out_size, void* d_ws,
                              size_t ws_size, hipStream_t stream) {
  const float* x      = (const float*)d_in[0];
  const float* ln1_g  = (const float*)d_in[1];
  const float* ln1_b  = (const float*)d_in[2];
  const float* qkv_w  = (const float*)d_in[3];
  const float* qkv_b  = (const float*)d_in[4];
  const float* proj_w = (const float*)d_in[5];
  const float* proj_b = (const float*)d_in[6];
  const float* ln2_g  = (const float*)d_in[7];
  const float* ln2_b  = (const float*)d_in[8];
  const float* fc1_w  = (const float*)d_in[9];
  const float* fc1_b  = (const float*)d_in[10];
  const float* fc2_w  = (const float*)d_in[11];
  const float* fc2_b  = (const float*)d_in[12];
  float* out = (float*)d_out;

  char* p = (char*)d_ws;
  u16* qkvwt  = (u16*)p;  p += (size_t)1152 * 384 * 2;
  u16* projwt = (u16*)p;  p += (size_t)384 * 384 * 2;
  u16* fc1wt  = (u16*)p;  p += (size_t)1536 * 384 * 2;
  u16* fc2wt  = (u16*)p;  p += (size_t)384 * 1536 * 2;
  float* x1   = (float*)p; p += (size_t)8192 * 384 * 4;
  u16* reg1   = (u16*)p;  p += (size_t)8192 * 384 * 2;   // h1 -> aout -> h2
  u16* reg2   = (u16*)p;  p += (size_t)8192 * 1536 * 2;  // q,k,vt -> h3
  u16* qd  = reg2;
  u16* kd  = reg2 + (size_t)24 * 2048 * 64;
  u16* vtd = kd + (size_t)24 * 2048 * 64;
  u16* h3  = reg2;

  prep_k<<<432 + 2048, 256, 0, stream>>>(qkv_w, qkvwt, proj_w, projwt,
                                         fc1_w, fc1wt, fc2_w, fc2wt,
                                         x, ln1_g, ln1_b, reg1);
  gemm_k<2, 2, 384, 18, 4><<<dim3(2304), 256, 0, stream>>>(
      reg1, qkvwt, qkv_b, nullptr, nullptr, 1152, qd, kd, vtd);
  attn_k<<<dim3(768), 256, 0, stream>>>(qd, kd, vtd, reg1);
  gemm_k<0, 2, 384, 6, 4><<<dim3(768), 256, 0, stream>>>(
      reg1, projwt, proj_b, x, x1, 384, nullptr, nullptr, nullptr);
  ln_k<<<2048, 256, 0, stream>>>(x1, ln2_g, ln2_b, reg1);
  gemm_k<1, 2, 384, 24, 4><<<dim3(3072), 256, 0, stream>>>(
      reg1, fc1wt, fc1_b, nullptr, h3, 1536, nullptr, nullptr, nullptr);
  gemm_k<0, 2, 1536, 6, 4><<<dim3(768), 256, 0, stream>>>(
      h3, fc2wt, fc2_b, x1, out, 384, nullptr, nullptr, nullptr);
}

// Round 21
// 119.944 us; speedup vs baseline: 1.2697x; 1.0012x over previous
//
#include <hip/hip_runtime.h>

typedef unsigned short u16;
typedef unsigned int u32;
typedef __bf16 bf16x8_t __attribute__((ext_vector_type(8)));
typedef float f32x4 __attribute__((ext_vector_type(4)));
typedef float f32x16 __attribute__((ext_vector_type(16)));

__device__ __forceinline__ u16 f2b(float f) {
  union { float f; u32 u; } v; v.f = f;
  u32 r = v.u + 0x7fffu + ((v.u >> 16) & 1u);
  return (u16)(r >> 16);
}

__device__ __forceinline__ u32 pkbf(float a, float b) {
  union { __bf16 h[2]; u32 u; } v;
  v.h[0] = (__bf16)a; v.h[1] = (__bf16)b;
  return v.u;
}

// fragment-major offset for bf16 activation matrices [M rows][Kd cols]:
// 16x8 tiles; a GEMM A-fragment wave-load is 1KB contiguous.
__device__ __forceinline__ size_t fmoff(int r, int c, int Kd) {
  return ((size_t)(r >> 4) * (Kd >> 3) + (c >> 3)) * 128 + (r & 15) * 8 + (c & 7);
}

__device__ __forceinline__ f32x4 mfma16(uint4 a, uint4 b, f32x4 c) {
  return __builtin_amdgcn_mfma_f32_16x16x32_bf16(
      __builtin_bit_cast(bf16x8_t, a), __builtin_bit_cast(bf16x8_t, b), c, 0, 0, 0);
}

__device__ __forceinline__ f32x16 mfma32(uint4 a, uint4 b, f32x16 c) {
  return __builtin_amdgcn_mfma_f32_32x32x16_bf16(
      __builtin_bit_cast(bf16x8_t, a), __builtin_bit_cast(bf16x8_t, b), c, 0, 0, 0);
}

__device__ __forceinline__ void plswap(u32& a, u32& b) {
  asm("v_permlane32_swap_b32 %0, %1" : "+v"(a), "+v"(b));
}

__device__ __forceinline__ void load_lds16(const void* g, void* l) {
  __builtin_amdgcn_global_load_lds(
      (const __attribute__((address_space(1))) unsigned int*)g,
      (__attribute__((address_space(3))) unsigned int*)l, 16, 0, 0);
}

template <int N>
__device__ __forceinline__ void waitvm() {
  if constexpr (N == 0) asm volatile("s_waitcnt vmcnt(0)" ::: "memory");
  else if constexpr (N == 4) asm volatile("s_waitcnt vmcnt(4)" ::: "memory");
  else if constexpr (N == 6) asm volatile("s_waitcnt vmcnt(6)" ::: "memory");
  else if constexpr (N == 8) asm volatile("s_waitcnt vmcnt(8)" ::: "memory");
  else asm volatile("s_waitcnt vmcnt(10)" ::: "memory");
}

// ---------------- LayerNorm row body: 384 f32 -> bf16 fragment-major --------
__device__ __forceinline__ void ln_body(const float* __restrict__ x,
                                        const float* __restrict__ g,
                                        const float* __restrict__ bta,
                                        u16* __restrict__ out, int row,
                                        int lane) {
  const float* xr = x + (size_t)row * 384;
  float v[6];
  float s = 0.f;
#pragma unroll
  for (int i = 0; i < 6; i++) { v[i] = xr[i * 64 + lane]; s += v[i]; }
#pragma unroll
  for (int off = 32; off >= 1; off >>= 1) s += __shfl_xor(s, off);
  float mean = s * (1.0f / 384.0f);
  float vs = 0.f;
#pragma unroll
  for (int i = 0; i < 6; i++) { float d = v[i] - mean; vs += d * d; }
#pragma unroll
  for (int off = 32; off >= 1; off >>= 1) vs += __shfl_xor(vs, off);
  float rstd = rsqrtf(vs * (1.0f / 384.0f) + 1e-5f);
#pragma unroll
  for (int i = 0; i < 6; i++) {
    int c = i * 64 + lane;
    out[fmoff(row, c, 384)] = f2b((v[i] - mean) * rstd * g[c] + bta[c]);
  }
}

__global__ __launch_bounds__(256) void ln_k(const float* __restrict__ x,
                                            const float* __restrict__ g,
                                            const float* __restrict__ bta,
                                            u16* __restrict__ out) {
  ln_body(x, g, bta, out, blockIdx.x * 4 + (threadIdx.x >> 6),
          threadIdx.x & 63);
}

// ---------------- prep: weight transposes (tiles 0..431) + ln1 (rest) -------
__global__ __launch_bounds__(256) void prep_k(
    const float* __restrict__ w0, u16* __restrict__ t0_,
    const float* __restrict__ w1, u16* __restrict__ t1_,
    const float* __restrict__ w2, u16* __restrict__ t2_,
    const float* __restrict__ w3, u16* __restrict__ t3_,
    const float* __restrict__ x, const float* __restrict__ g,
    const float* __restrict__ bta, u16* __restrict__ lnout) {
  __shared__ u16 L[64][68];
  int tile = blockIdx.x, tid = threadIdx.x;
  if (tile >= 432) {
    ln_body(x, g, bta, lnout, (tile - 432) * 4 + (tid >> 6), tid & 63);
    return;
  }
  const float* w; u16* wt; int K, N, rel;
  if (tile < 108)      { w = w0; wt = t0_; K = 384;  N = 1152; rel = tile; }
  else if (tile < 144) { w = w1; wt = t1_; K = 384;  N = 384;  rel = tile - 108; }
  else if (tile < 288) { w = w2; wt = t2_; K = 384;  N = 1536; rel = tile - 144; }
  else                 { w = w3; wt = t3_; K = 1536; N = 384;  rel = tile - 288; }
  int ntx = N >> 6;
  int tk = (rel / ntx) << 6, tn = (rel - (rel / ntx) * ntx) << 6;

  int r = tid >> 2, c0 = (tid & 3) << 4;
  const float* src = w + (size_t)(tk + r) * N + tn + c0;
#pragma unroll
  for (int j = 0; j < 16; j += 4) {
    float4 a = *(const float4*)(src + j);
    L[r][c0 + j + 0] = f2b(a.x);
    L[r][c0 + j + 1] = f2b(a.y);
    L[r][c0 + j + 2] = f2b(a.z);
    L[r][c0 + j + 3] = f2b(a.w);
  }
  __syncthreads();
  int n = tid >> 2, k0 = (tid & 3) << 4;
  u16 tmp[16];
#pragma unroll
  for (int j = 0; j < 16; j++) tmp[j] = L[k0 + j][n];
  u16* dst = wt + (size_t)(tn + n) * K + tk + k0;
  *(uint4*)dst = *(const uint4*)(tmp);
  *(uint4*)(dst + 8) = *(const uint4*)(tmp + 8);
}

// ---------------- GEMM: A fragment-major direct-to-reg, B LDS triple-buffer -
// 1D grid with XCD swizzle: all NX col-blocks of a row-panel land on the
// same XCD (A-panel fetched once per L2). BM = MR*32, BN = 64, BK = 64.
template <int EPI, int MR, int KD, int NX, int MINW>
__global__ __launch_bounds__(256, MINW) void gemm_k(
    const u16* __restrict__ A, const u16* __restrict__ Bt,
    const float* __restrict__ bias, const float* __restrict__ res,
    void* __restrict__ outp, int Nn,
    u16* __restrict__ qp, u16* __restrict__ kp, u16* __restrict__ vtp) {
  constexpr int NS = KD / 64;
  constexpr int KD8 = KD / 8;
  __shared__ __align__(16) u16 Bs[3][64 * 64];
  int tid = threadIdx.x;
  int lane = tid & 63, wid = tid >> 6;
  int li = lane & 15, lg = lane >> 4;
  int wr = wid >> 1, wc = wid & 1;

  int p = blockIdx.x;
  int idx = p >> 3;
  int cx = idx % NX;
  int row0 = ((p & 7) + ((idx / NX) << 3)) * (MR * 32);
  int col0 = cx * 64;

  int lr = lane >> 3;
  int sc8 = ((lane & 7) ^ lr) * 8;    // pre-swizzled B source chunk (u16)

  const u16* Ab = A + ((size_t)(row0 / 16 + wr * MR) * KD8 + lg) * 128 + li * 8;

  f32x4 z = {0.f, 0.f, 0.f, 0.f};
  f32x4 acc[MR][2];
#pragma unroll
  for (int m = 0; m < MR; m++)
#pragma unroll
    for (int n = 0; n < 2; n++) acc[m][n] = z;

  uint4 af0[MR][2], af1[MR][2];

  auto stageB = [&](int buf, int k0) {
#pragma unroll
    for (int j = 0; j < 2; j++) {
      int ib = wid * 2 + j;
      load_lds16(Bt + (size_t)(col0 + ib * 8 + lr) * KD + k0 + sc8,
                 (char*)Bs[buf] + ib * 1024);
    }
  };
  auto loadA = [&](uint4 (*dst)[2], int t) {
#pragma unroll
    for (int m = 0; m < MR; m++)
#pragma unroll
      for (int kk = 0; kk < 2; kk++)
        dst[m][kk] =
            *(const uint4*)(Ab + ((size_t)m * KD8 + t * 8 + kk * 4) * 128);
  };

  stageB(0, 0);
  stageB(1, 64);
  loadA(af0, 0);
  if (NS > 1) loadA(af1, 1);
  waitvm<2 * MR>();   // B0,B1,A0 done; A1 in flight
  __builtin_amdgcn_s_barrier();
  asm volatile("" ::: "memory");

#pragma unroll
  for (int t = 0; t < NS; t++) {
    if (t + 2 < NS) stageB((t + 2) % 3, (t + 2) * 64);
    const char* Bsb = (const char*)Bs[t % 3];
#pragma unroll
    for (int kk = 0; kk < 2; kk++) {
      uint4 bf[2];
#pragma unroll
      for (int n = 0; n < 2; n++) {
        int c = wc * 32 + n * 16 + li;
        bf[n] = *(const uint4*)(Bsb + c * 128 +
                                ((kk * 64 + lg * 16) ^ ((c & 7) << 4)));
      }
#pragma unroll
      for (int m = 0; m < MR; m++)
#pragma unroll
        for (int n = 0; n < 2; n++)
          acc[m][n] = mfma16((t & 1) ? af1[m][kk] : af0[m][kk], bf[n],
                             acc[m][n]);
    }
    if (t + 2 < NS) {
      if (t & 1) loadA(af1, t + 2);
      else       loadA(af0, t + 2);
      waitvm<2 + 2 * MR>();   // (t+1)'s B and A landed; (t+2) in flight
      __builtin_amdgcn_s_barrier();
      asm volatile("" ::: "memory");
    } else if (t + 1 < NS) {
      waitvm<0>();
      __builtin_amdgcn_s_barrier();
      asm volatile("" ::: "memory");
    }
  }

#pragma unroll
  for (int m = 0; m < MR; m++) {
#pragma unroll
    for (int n = 0; n < 2; n++) {
#pragma unroll
      for (int j = 0; j < 4; j++) {
        int r = row0 + wr * (MR * 16) + m * 16 + lg * 4 + j;
        int c = col0 + wc * 32 + n * 16 + li;
        float v = acc[m][n][j] + bias[c];
        if (EPI == 0) {
          ((float*)outp)[(size_t)r * Nn + c] = v + res[(size_t)r * Nn + c];
        } else if (EPI == 1) {
          float e = __expf(-1.5957691f * v * (1.f + 0.044715f * v * v));
          ((u16*)outp)[fmoff(r, c, Nn)] = f2b(v / (1.f + e));
        } else {
          int tt = c / 384;
          int c2 = c - tt * 384;
          int hh = c2 >> 6, d = c2 & 63;
          int bb = r >> 11, nn = r & 2047;
          size_t bh = (size_t)bb * 6 + hh;
          int tile = nn >> 5;
          if (tt == 2) {
            int kvl = nn & 31;
            int kvHalf = (kvl >> 4) & 1, h2 = (kvl >> 3) & 1, jj = kvl & 7;
            int dTile = d >> 5, l31 = d & 31;
            vtp[(((bh * 64 + tile) * 2 + dTile) * 2 + kvHalf) * 512 +
                (l31 + h2 * 32) * 8 + jj] = f2b(v);
          } else {
            int chunk = d >> 4, h2 = (d >> 3) & 1, e = d & 7;
            int l31 = nn & 31;
            size_t off = ((bh * 64 + tile) * 4 + chunk) * 512 +
                         (l31 + h2 * 32) * 8 + e;
            if (tt == 0) qp[off] = f2b(v * 0.18033688f);  // 0.125 * log2(e)
            else         kp[off] = f2b(v);
          }
        }
      }
    }
  }
}

// ---------------- flash attention: 64 q-rows/block, 2 q-tiles/wave ----------
// q/k/vt fragment-major; q pre-scaled by 0.125*log2e so P = exp2(S).
// 4 waves = 4 kv-quarters; K prefetched one tile ahead, V loaded at top.
// THIS ROUND: the two q-tiles' S-chains, softmax, and PV are explicitly
// interleaved (independent chains -> 2x MFMA ILP per wave).
__global__ __launch_bounds__(256, 2) void attn_k(const u16* __restrict__ q,
                                                 const u16* __restrict__ k,
                                                 const u16* __restrict__ vt,
                                                 u16* __restrict__ out) {
  __shared__ __align__(16) float Ol[3][2][16][64];  // 24 KB, reused per tile
  __shared__ float Ls[3][64];

  int tid = threadIdx.x;
  int lane = tid & 63, wid = tid >> 6;
  int l31 = lane & 31, hi = lane >> 5;
  int bid = blockIdx.x;
  int nid = (bid & 7) * 96 + (bid >> 3);   // XCD swizzle: 768 = 8 XCD * 96
  int bh = nid >> 5, qT = nid & 31;
  int b = bh / 6, hh = bh - b * 6;
  int qb = qT * 64;

  const u16* qp_ = q + ((size_t)bh * 64 + qT * 2) * 2048 + lane * 8;
  const u16* kp_ = k + ((size_t)bh * 64 + wid * 16) * 2048 + lane * 8;
  const u16* vp_ = vt + ((size_t)bh * 64 + wid * 16) * 2048 + lane * 8;

  uint4 qf0[4], qf1[4], kf[4];
#pragma unroll
  for (int c = 0; c < 4; c++) qf0[c] = *(const uint4*)(qp_ + c * 512);
#pragma unroll
  for (int c = 0; c < 4; c++) qf1[c] = *(const uint4*)(qp_ + 2048 + c * 512);
#pragma unroll
  for (int c = 0; c < 4; c++) kf[c] = *(const uint4*)(kp_ + c * 512);
  kp_ += 2048;

  f32x16 o00, o01, o10, o11;
#pragma unroll
  for (int r = 0; r < 16; r++) {
    o00[r] = 0.f; o01[r] = 0.f; o10[r] = 0.f; o11[r] = 0.f;
  }
  float ls0 = 0.f, ls1 = 0.f;

#pragma unroll
  for (int t = 0; t < 16; t++) {
    // V fragments for this tile (shared by both q-tiles)
    uint4 vf0 = *(const uint4*)(vp_);
    uint4 vf1 = *(const uint4*)(vp_ + 512);
    uint4 vf2 = *(const uint4*)(vp_ + 1024);
    uint4 vf3 = *(const uint4*)(vp_ + 1536);
    // prefetch next tile's K
    uint4 kn[4];
    if (t < 15) {
#pragma unroll
      for (int c = 0; c < 4; c++) kn[c] = *(const uint4*)(kp_ + c * 512);
    }

    // ---- both q-tiles, interleaved S-chains (independent MFMA chains) ----
    f32x16 s0, s1;
#pragma unroll
    for (int r = 0; r < 16; r++) { s0[r] = 0.f; s1[r] = 0.f; }
#pragma unroll
    for (int c = 0; c < 4; c++) {
      s0 = mfma32(kf[c], qf0[c], s0);
      s1 = mfma32(kf[c], qf1[c], s1);
    }

    // softmax both tiles
    float p0[16], p1[16];
#pragma unroll
    for (int r = 0; r < 16; r++) {
      p0[r] = __builtin_amdgcn_exp2f(s0[r]);
      p1[r] = __builtin_amdgcn_exp2f(s1[r]);
    }
    ls0 += ((p0[0] + p0[1]) + (p0[2] + p0[3])) +
           ((p0[4] + p0[5]) + (p0[6] + p0[7])) +
           ((p0[8] + p0[9]) + (p0[10] + p0[11])) +
           ((p0[12] + p0[13]) + (p0[14] + p0[15]));
    ls1 += ((p1[0] + p1[1]) + (p1[2] + p1[3])) +
           ((p1[4] + p1[5]) + (p1[6] + p1[7])) +
           ((p1[8] + p1[9]) + (p1[10] + p1[11])) +
           ((p1[12] + p1[13]) + (p1[14] + p1[15]));

    // pack both
    u32 u0[8], u1[8];
#pragma unroll
    for (int i = 0; i < 8; i++) {
      u0[i] = pkbf(p0[2 * i], p0[2 * i + 1]);
      u1[i] = pkbf(p1[2 * i], p1[2 * i + 1]);
    }
    plswap(u0[0], u0[2]); plswap(u0[1], u0[3]);
    plswap(u0[4], u0[6]); plswap(u0[5], u0[7]);
    plswap(u1[0], u1[2]); plswap(u1[1], u1[3]);
    plswap(u1[4], u1[6]); plswap(u1[5], u1[7]);
    uint4 pa00 = {u0[0], u0[1], u0[2], u0[3]};
    uint4 pa01 = {u0[4], u0[5], u0[6], u0[7]};
    uint4 pa10 = {u1[0], u1[1], u1[2], u1[3]};
    uint4 pa11 = {u1[4], u1[5], u1[6], u1[7]};

    // PV, interleaved across the 4 independent o-accumulators
    o00 = mfma32(pa00, vf0, o00);
    o10 = mfma32(pa10, vf0, o10);
    o01 = mfma32(pa00, vf2, o01);
    o11 = mfma32(pa10, vf2, o11);
    o00 = mfma32(pa01, vf1, o00);
    o10 = mfma32(pa11, vf1, o10);
    o01 = mfma32(pa01, vf3, o01);
    o11 = mfma32(pa11, vf3, o11);

    if (t < 15) {
#pragma unroll
      for (int c = 0; c < 4; c++) kf[c] = kn[c];
    }
    kp_ += 2048;
    vp_ += 2048;
  }

  ls0 += __shfl_xor(ls0, 32);
  ls1 += __shfl_xor(ls1, 32);

  // ---- combine, q-tile 0 ----
  if (wid) {
#pragma unroll
    for (int r = 0; r < 16; r++) {
      Ol[wid - 1][0][r][lane] = o00[r];
      Ol[wid - 1][1][r][lane] = o01[r];
    }
    Ls[wid - 1][lane] = ls0;
  }
  __syncthreads();
  if (wid == 0) {
#pragma unroll
    for (int w = 0; w < 3; w++) ls0 += Ls[w][lane];
#pragma unroll
    for (int r = 0; r < 16; r++)
#pragma unroll
      for (int w = 0; w < 3; w++) {
        o00[r] += Ol[w][0][r][lane];
        o01[r] += Ol[w][1][r][lane];
      }
    float rl = 1.0f / ls0;
#pragma unroll
    for (int r = 0; r < 16; r++) {
      int qo = (r & 3) + 8 * (r >> 2) + hi * 4;
      float rlq = __shfl(rl, qo, 64);
      int row = b * 2048 + qb + qo;
      out[fmoff(row, hh * 64 + l31, 384)] = f2b(o00[r] * rlq);
      out[fmoff(row, hh * 64 + 32 + l31, 384)] = f2b(o01[r] * rlq);
    }
  }
  __syncthreads();
  // ---- combine, q-tile 1 ----
  if (wid) {
#pragma unroll
    for (int r = 0; r < 16; r++) {
      Ol[wid - 1][0][r][lane] = o10[r];
      Ol[wid - 1][1][r][lane] = o11[r];
    }
    Ls[wid - 1][lane] = ls1;
  }
  __syncthreads();
  if (wid == 0) {
#pragma unroll
    for (int w = 0; w < 3; w++) ls1 += Ls[w][lane];
#pragma unroll
    for (int r = 0; r < 16; r++)
#pragma unroll
      for (int w = 0; w < 3; w++) {
        o10[r] += Ol[w][0][r][lane];
        o11[r] += Ol[w][1][r][lane];
      }
    float rl = 1.0f / ls1;
#pragma unroll
    for (int r = 0; r < 16; r++) {
      int qo = (r & 3) + 8 * (r >> 2) + hi * 4;
      float rlq = __shfl(rl, qo, 64);
      int row = b * 2048 + qb + 32 + qo;
      out[fmoff(row, hh * 64 + l31, 384)] = f2b(o10[r] * rlq);
      out[fmoff(row, hh * 64 + 32 + l31, 384)] = f2b(o11[r] * rlq);
    }
  }
}

// ---------------------------------------------------------------------------
extern "C" void kernel_launch(void* const* d_in, const int* in_sizes, int n_in,
                              void* d_out, int out_size, void* d_ws,
                              size_t ws_size, hipStream_t stream) {
  const float* x      = (const float*)d_in[0];
  const float* ln1_g  = (const float*)d_in[1];
  const float* ln1_b  = (const float*)d_in[2];
  const float* qkv_w  = (const float*)d_in[3];
  const float* qkv_b  = (const float*)d_in[4];
  const float* proj_w = (const float*)d_in[5];
  const float* proj_b = (const float*)d_in[6];
  const float* ln2_g  = (const float*)d_in[7];
  const float* ln2_b  = (const float*)d_in[8];
  const float* fc1_w  = (const float*)d_in[9];
  const float* fc1_b  = (const float*)d_in[10];
  const float* fc2_w  = (const float*)d_in[11];
  const float* fc2_b  = (const float*)d_in[12];
  float* out = (float*)d_out;

  char* p = (char*)d_ws;
  u16* qkvwt  = (u16*)p;  p += (size_t)1152 * 384 * 2;
  u16* projwt = (u16*)p;  p += (size_t)384 * 384 * 2;
  u16* fc1wt  = (u16*)p;  p += (size_t)1536 * 384 * 2;
  u16* fc2wt  = (u16*)p;  p += (size_t)384 * 1536 * 2;
  float* x1   = (float*)p; p += (size_t)8192 * 384 * 4;
  u16* reg1   = (u16*)p;  p += (size_t)8192 * 384 * 2;   // h1 -> aout -> h2
  u16* reg2   = (u16*)p;  p += (size_t)8192 * 1536 * 2;  // q,k,vt -> h3
  u16* qd  = reg2;
  u16* kd  = reg2 + (size_t)24 * 2048 * 64;
  u16* vtd = kd + (size_t)24 * 2048 * 64;
  u16* h3  = reg2;

  prep_k<<<432 + 2048, 256, 0, stream>>>(qkv_w, qkvwt, proj_w, projwt,
                                         fc1_w, fc1wt, fc2_w, fc2wt,
                                         x, ln1_g, ln1_b, reg1);
  gemm_k<2, 2, 384, 18, 4><<<dim3(2304), 256, 0, stream>>>(
      reg1, qkvwt, qkv_b, nullptr, nullptr, 1152, qd, kd, vtd);
  attn_k<<<dim3(768), 256, 0, stream>>>(qd, kd, vtd, reg1);
  gemm_k<0, 2, 384, 6, 4><<<dim3(768), 256, 0, stream>>>(
      reg1, projwt, proj_b, x, x1, 384, nullptr, nullptr, nullptr);
  ln_k<<<2048, 256, 0, stream>>>(x1, ln2_g, ln2_b, reg1);
  gemm_k<1, 2, 384, 24, 4><<<dim3(3072), 256, 0, stream>>>(
      reg1, fc1wt, fc1_b, nullptr, h3, 1536, nullptr, nullptr, nullptr);
  gemm_k<0, 2, 1536, 6, 4><<<dim3(768), 256, 0, stream>>>(
      h3, fc2wt, fc2_b, x1, out, 384, nullptr, nullptr, nullptr);
}